// Round 1
// baseline (2076.360 us; speedup 1.0000x reference)
//
#include <hip/hip_runtime.h>
#include <math.h>

// Problem constants
static constexpr int kB = 2;
static constexpr int kS = 2048;
static constexpr int kE = 1024;
static constexpr int kH = 16;
static constexpr int kD = 64;
static constexpr int kTRIL = 2080; // 64*65/2

// ---------------------------------------------------------------------------
// Kernel 1: Wqk[h] = L_h @ L_h^T from packed lower-triangular params.
// params[h, i*(i+1)/2 + k] = L[i][k], k <= i (row-major tril indices).
// Wqk[h][i][j] = sum_{k<=min(i,j)} L[i][k]*L[j][k]
// ---------------------------------------------------------------------------
__global__ __launch_bounds__(256) void build_wqk(
    const float* __restrict__ params, float* __restrict__ wqk)
{
    __shared__ float p[kTRIL];
    const int h = blockIdx.x;
    for (int i = threadIdx.x; i < kTRIL; i += 256) p[i] = params[h * kTRIL + i];
    __syncthreads();
    for (int idx = threadIdx.x; idx < kD * kD; idx += 256) {
        const int i = idx >> 6;
        const int j = idx & 63;
        const int m = i < j ? i : j;
        const float* pi = p + (i * (i + 1)) / 2;
        const float* pj = p + (j * (j + 1)) / 2;
        float s = 0.f;
        for (int k = 0; k <= m; ++k) s += pi[k] * pj[k];
        wqk[h * kD * kD + idx] = s;
    }
}

// ---------------------------------------------------------------------------
// Kernel 2: Q[bs, h*64+e] = (sum_d x[bs, h*64+d] * Wqk[h][d][e]) * 0.125
// (score scale 1/sqrt(64) folded into Q). One block per token.
// ---------------------------------------------------------------------------
__global__ __launch_bounds__(256) void q_proj(
    const float* __restrict__ x, const float* __restrict__ wqk,
    float* __restrict__ Q)
{
    __shared__ float xs[kE];
    const int bs = blockIdx.x;
    const int tid = threadIdx.x;
    ((float4*)xs)[tid] = ((const float4*)(x + (size_t)bs * kE))[tid];
    __syncthreads();
    const int o = tid * 4;         // output base (4 outputs per thread)
    const int h = o >> 6;
    const int e = o & 63;
    const float* W = wqk + h * kD * kD;
    float a0 = 0.f, a1 = 0.f, a2 = 0.f, a3 = 0.f;
    const float* xh = xs + h * kD;
#pragma unroll 8
    for (int d = 0; d < kD; ++d) {
        const float xv = xh[d];
        const float4 w = *(const float4*)(W + d * kD + e);
        a0 += xv * w.x; a1 += xv * w.y; a2 += xv * w.z; a3 += xv * w.w;
    }
    float4 r;
    r.x = a0 * 0.125f; r.y = a1 * 0.125f; r.z = a2 * 0.125f; r.w = a3 * 0.125f;
    ((float4*)(Q + (size_t)bs * kE))[tid] = r;
}

// ---------------------------------------------------------------------------
// Kernel 3/5: C[M,N] = A[M,K] @ Bw[N,K]^T + bias[N]   (all row-major, f32)
// 64x64 tile, 256 threads, 4x4 microtile, BK=16.
// ---------------------------------------------------------------------------
__global__ __launch_bounds__(256) void gemm_bt_bias(
    const float* __restrict__ A, const float* __restrict__ Bw,
    const float* __restrict__ bias, float* __restrict__ C,
    int M, int N, int K)
{
    __shared__ float As[16][64 + 1];
    __shared__ float Bs[16][64 + 1];
    const int bm = blockIdx.y * 64;
    const int bn = blockIdx.x * 64;
    const int tid = threadIdx.x;
    const int tx = tid & 15;       // 0..15  -> N
    const int ty = tid >> 4;       // 0..15  -> M
    float acc[4][4] = {};
    for (int k0 = 0; k0 < K; k0 += 16) {
#pragma unroll
        for (int r = 0; r < 4; ++r) {
            const int row = (tid >> 4) + r * 16;
            const int kk = tid & 15;
            As[kk][row] = A[(size_t)(bm + row) * K + k0 + kk];
            Bs[kk][row] = Bw[(size_t)(bn + row) * K + k0 + kk];
        }
        __syncthreads();
#pragma unroll
        for (int kk = 0; kk < 16; ++kk) {
            float a[4], b[4];
#pragma unroll
            for (int i = 0; i < 4; ++i) a[i] = As[kk][ty * 4 + i];
#pragma unroll
            for (int j = 0; j < 4; ++j) b[j] = Bs[kk][tx * 4 + j];
#pragma unroll
            for (int i = 0; i < 4; ++i)
#pragma unroll
                for (int j = 0; j < 4; ++j) acc[i][j] += a[i] * b[j];
        }
        __syncthreads();
    }
#pragma unroll
    for (int i = 0; i < 4; ++i) {
        const int row = bm + ty * 4 + i;
#pragma unroll
        for (int j = 0; j < 4; ++j) {
            const int col = bn + tx * 4 + j;
            C[(size_t)row * N + col] = acc[i][j] + bias[col];
        }
    }
}

// ---------------------------------------------------------------------------
// Kernel 4: flash attention, f32. Q pre-scaled by 1/8. Keys are x itself,
// values from V buffer. One block = one (b, h, 32-query tile).
// Thread layout: q = tid/8 (0..31), c = tid%8; thread owns score cols
// c*8..c*8+7 and output dims c*8..c*8+7 of query row q.
// ---------------------------------------------------------------------------
__global__ __launch_bounds__(256) void flash_attn(
    const float* __restrict__ Q, const float* __restrict__ x,
    const float* __restrict__ V, float* __restrict__ O)
{
    constexpr int BQ = 32, BK = 64;
    const int q0 = blockIdx.x * BQ;
    const int h = blockIdx.y;
    const int b = blockIdx.z;

    __shared__ float Qs[BQ][kD + 1];
    __shared__ float Ks[BK][kD + 1];
    __shared__ float Vs[BK][kD + 1];
    __shared__ float Ps[BQ][BK + 1];

    const int tid = threadIdx.x;
    const int q = tid >> 3;
    const int c = tid & 7;

    // Load Q tile (32x64): thread loads rows tid/16 and tid/16+16, 4 floats each
    {
        const int row = tid >> 4;
        const int col = (tid & 15) * 4;
        const float* src = Q + ((size_t)(b * kS + q0 + row) * kE) + h * kD + col;
        float4 v0 = *(const float4*)src;
        Qs[row][col] = v0.x; Qs[row][col + 1] = v0.y;
        Qs[row][col + 2] = v0.z; Qs[row][col + 3] = v0.w;
        float4 v1 = *(const float4*)(src + (size_t)16 * kE);
        Qs[row + 16][col] = v1.x; Qs[row + 16][col + 1] = v1.y;
        Qs[row + 16][col + 2] = v1.z; Qs[row + 16][col + 3] = v1.w;
    }

    float m = -INFINITY, l = 0.f;
    float o[8] = {0.f, 0.f, 0.f, 0.f, 0.f, 0.f, 0.f, 0.f};

    for (int k0 = 0; k0 < kS; k0 += BK) {
        __syncthreads();   // previous PV done; safe to overwrite Ks/Vs/Ps
        // Load K (=x head slice) and V tiles: 64x64 each, 16 floats/thread
        {
            const int row = tid >> 2;
            const int col = (tid & 3) * 16;
            const size_t base = ((size_t)(b * kS + k0 + row) * kE) + h * kD + col;
            const float* ksrc = x + base;
            const float* vsrc = V + base;
#pragma unroll
            for (int j = 0; j < 4; ++j) {
                float4 t = *(const float4*)(ksrc + j * 4);
                Ks[row][col + j * 4 + 0] = t.x; Ks[row][col + j * 4 + 1] = t.y;
                Ks[row][col + j * 4 + 2] = t.z; Ks[row][col + j * 4 + 3] = t.w;
                float4 u = *(const float4*)(vsrc + j * 4);
                Vs[row][col + j * 4 + 0] = u.x; Vs[row][col + j * 4 + 1] = u.y;
                Vs[row][col + j * 4 + 2] = u.z; Vs[row][col + j * 4 + 3] = u.w;
            }
        }
        __syncthreads();

        // Scores: s[j] = Qs[q][:] . Ks[c*8+j][:]
        float s[8] = {0.f, 0.f, 0.f, 0.f, 0.f, 0.f, 0.f, 0.f};
#pragma unroll 8
        for (int d = 0; d < kD; ++d) {
            const float qv = Qs[q][d];
#pragma unroll
            for (int j = 0; j < 8; ++j) s[j] += qv * Ks[c * 8 + j][d];
        }

        // Online softmax across the 8 lanes owning row q
        float tmax = s[0];
#pragma unroll
        for (int j = 1; j < 8; ++j) tmax = fmaxf(tmax, s[j]);
#pragma unroll
        for (int mask = 1; mask < 8; mask <<= 1)
            tmax = fmaxf(tmax, __shfl_xor(tmax, mask, 64));
        const float mnew = fmaxf(m, tmax);
        float p[8], tsum = 0.f;
#pragma unroll
        for (int j = 0; j < 8; ++j) { p[j] = expf(s[j] - mnew); tsum += p[j]; }
#pragma unroll
        for (int mask = 1; mask < 8; mask <<= 1)
            tsum += __shfl_xor(tsum, mask, 64);
        const float alpha = expf(m - mnew);
        l = l * alpha + tsum;
        m = mnew;
#pragma unroll
        for (int jj = 0; jj < 8; ++jj) o[jj] *= alpha;
#pragma unroll
        for (int j = 0; j < 8; ++j) Ps[q][c * 8 + j] = p[j];
        __syncthreads();

        // PV: o[jj] += sum_t P[q][t] * Vs[t][c*8+jj]
#pragma unroll 8
        for (int t = 0; t < BK; ++t) {
            const float pv = Ps[q][t];
#pragma unroll
            for (int jj = 0; jj < 8; ++jj) o[jj] += pv * Vs[t][c * 8 + jj];
        }
    }

    const float inv = 1.f / l;
    float* dst = O + ((size_t)(b * kS + q0 + q) * kE) + h * kD + c * 8;
#pragma unroll
    for (int jj = 0; jj < 8; ++jj) dst[jj] = o[jj] * inv;
}

// ---------------------------------------------------------------------------
extern "C" void kernel_launch(void* const* d_in, const int* in_sizes, int n_in,
                              void* d_out, int out_size, void* d_ws, size_t ws_size,
                              hipStream_t stream) {
    (void)in_sizes; (void)n_in; (void)out_size; (void)ws_size;
    const float* x      = (const float*)d_in[0];
    const float* params = (const float*)d_in[1];
    const float* Wv     = (const float*)d_in[2];
    const float* bv     = (const float*)d_in[3];
    const float* Wo     = (const float*)d_in[4];
    const float* bo     = (const float*)d_in[5];
    float* out = (float*)d_out;

    char* ws = (char*)d_ws;
    float* wqk = (float*)ws;                                  // 256 KB
    float* Q   = (float*)(ws + 262144);                       // 16 MB
    float* V   = Q + (size_t)kB * kS * kE;                    // 16 MB
    float* AO  = V + (size_t)kB * kS * kE;                    // 16 MB

    build_wqk<<<kH, 256, 0, stream>>>(params, wqk);
    q_proj<<<kB * kS, 256, 0, stream>>>(x, wqk, Q);
    gemm_bt_bias<<<dim3(kE / 64, (kB * kS) / 64), 256, 0, stream>>>(
        x, Wv, bv, V, kB * kS, kE, kE);
    flash_attn<<<dim3(kS / 32, kH, kB), 256, 0, stream>>>(Q, x, V, AO);
    gemm_bt_bias<<<dim3(kE / 64, (kB * kS) / 64), 256, 0, stream>>>(
        AO, Wo, bo, out, kB * kS, kE, kE);
}

// Round 2
// 528.337 us; speedup vs baseline: 3.9300x; 3.9300x over previous
//
#include <hip/hip_runtime.h>
#include <math.h>

// Problem constants
static constexpr int kB = 2;
static constexpr int kS = 2048;
static constexpr int kE = 1024;
static constexpr int kH = 16;
static constexpr int kD = 64;
static constexpr int kTRIL = 2080; // 64*65/2

typedef __attribute__((ext_vector_type(8))) __bf16 bf16x8;
typedef __attribute__((ext_vector_type(4))) __bf16 bf16x4;
typedef __attribute__((ext_vector_type(4))) float f32x4;

// Split f32 into bf16 hi (truncation) + bf16 lo (RNE of residual).
__device__ __forceinline__ void split_bf16(float f, __bf16& hi, __bf16& lo) {
    unsigned bits = __builtin_bit_cast(unsigned, f);
    hi = __builtin_bit_cast(__bf16, (unsigned short)(bits >> 16));
    float hf = __builtin_bit_cast(float, bits & 0xFFFF0000u);
    lo = (__bf16)(f - hf);
}

// ---------------------------------------------------------------------------
// Kernel 1: Wqk[h] = L_h @ L_h^T from packed lower-triangular params.
// ---------------------------------------------------------------------------
__global__ __launch_bounds__(256) void build_wqk(
    const float* __restrict__ params, float* __restrict__ wqk)
{
    __shared__ float p[kTRIL];
    const int h = blockIdx.x;
    for (int i = threadIdx.x; i < kTRIL; i += 256) p[i] = params[h * kTRIL + i];
    __syncthreads();
    for (int idx = threadIdx.x; idx < kD * kD; idx += 256) {
        const int i = idx >> 6;
        const int j = idx & 63;
        const int m = i < j ? i : j;
        const float* pi = p + (i * (i + 1)) / 2;
        const float* pj = p + (j * (j + 1)) / 2;
        float s = 0.f;
        for (int k = 0; k <= m; ++k) s += pi[k] * pj[k];
        wqk[h * kD * kD + idx] = s;
    }
}

// ---------------------------------------------------------------------------
// Kernel 2: Q = (xh @ Wqk) * 0.125 * log2(e)   (softmax done in exp2 space)
// ---------------------------------------------------------------------------
__global__ __launch_bounds__(256) void q_proj(
    const float* __restrict__ x, const float* __restrict__ wqk,
    float* __restrict__ Q)
{
    __shared__ float xs[kE];
    const int bs = blockIdx.x;
    const int tid = threadIdx.x;
    ((float4*)xs)[tid] = ((const float4*)(x + (size_t)bs * kE))[tid];
    __syncthreads();
    const int o = tid * 4;
    const int h = o >> 6;
    const int e = o & 63;
    const float* W = wqk + h * kD * kD;
    float a0 = 0.f, a1 = 0.f, a2 = 0.f, a3 = 0.f;
    const float* xh = xs + h * kD;
#pragma unroll 8
    for (int d = 0; d < kD; ++d) {
        const float xv = xh[d];
        const float4 w = *(const float4*)(W + d * kD + e);
        a0 += xv * w.x; a1 += xv * w.y; a2 += xv * w.z; a3 += xv * w.w;
    }
    const float sc = 0.125f * 1.44269504088896340736f;
    float4 r;
    r.x = a0 * sc; r.y = a1 * sc; r.z = a2 * sc; r.w = a3 * sc;
    ((float4*)(Q + (size_t)bs * kE))[tid] = r;
}

// ---------------------------------------------------------------------------
// Kernel 3/5: C[M,N] = A[M,K] @ Bw[N,K]^T + bias[N]   (f32, VALU)
// ---------------------------------------------------------------------------
__global__ __launch_bounds__(256) void gemm_bt_bias(
    const float* __restrict__ A, const float* __restrict__ Bw,
    const float* __restrict__ bias, float* __restrict__ C,
    int M, int N, int K)
{
    __shared__ float As[16][64 + 1];
    __shared__ float Bs[16][64 + 1];
    const int bm = blockIdx.y * 64;
    const int bn = blockIdx.x * 64;
    const int tid = threadIdx.x;
    const int tx = tid & 15;
    const int ty = tid >> 4;
    float acc[4][4] = {};
    for (int k0 = 0; k0 < K; k0 += 16) {
#pragma unroll
        for (int r = 0; r < 4; ++r) {
            const int row = (tid >> 4) + r * 16;
            const int kk = tid & 15;
            As[kk][row] = A[(size_t)(bm + row) * K + k0 + kk];
            Bs[kk][row] = Bw[(size_t)(bn + row) * K + k0 + kk];
        }
        __syncthreads();
#pragma unroll
        for (int kk = 0; kk < 16; ++kk) {
            float a[4], b[4];
#pragma unroll
            for (int i = 0; i < 4; ++i) a[i] = As[kk][ty * 4 + i];
#pragma unroll
            for (int j = 0; j < 4; ++j) b[j] = Bs[kk][tx * 4 + j];
#pragma unroll
            for (int i = 0; i < 4; ++i)
#pragma unroll
                for (int j = 0; j < 4; ++j) acc[i][j] += a[i] * b[j];
        }
        __syncthreads();
    }
#pragma unroll
    for (int i = 0; i < 4; ++i) {
        const int row = bm + ty * 4 + i;
#pragma unroll
        for (int j = 0; j < 4; ++j) {
            const int col = bn + tx * 4 + j;
            C[(size_t)row * N + col] = acc[i][j] + bias[col];
        }
    }
}

// ---------------------------------------------------------------------------
// Kernel 4: MFMA flash attention (swapped-operand), split-bf16 QK^T.
// Block = 256 thr = 4 waves; BQ=64 (16 q/wave); BK=64.
// All LDS tiles: rows of 64 bf16 (128B), 16B-chunk XOR swizzle chunk^(row&7).
// ---------------------------------------------------------------------------
__global__ __launch_bounds__(256) void flash_attn_mfma(
    const float* __restrict__ Q, const float* __restrict__ x,
    const float* __restrict__ V, float* __restrict__ O)
{
    __shared__ __bf16 Ksh[64 * 64];
    __shared__ __bf16 Ksl[64 * 64];
    __shared__ __bf16 Vt[64 * 64];      // V transposed: Vt[d][key]
    __shared__ __bf16 Pl[4][16 * 64];   // per-wave P[q][key]

    const int tid = threadIdx.x;
    const int l = tid & 63;
    const int w = tid >> 6;
    const int g = l >> 4;     // 0..3
    const int lm = l & 15;
    const int q0 = blockIdx.x * 64;
    const int h = blockIdx.y;
    const int b = blockIdx.z;

    // Q fragments (hi/lo), persistent: Q[q = q0+16w+lm][d = g*8 + j + 32*ks]
    bf16x8 qh[2], ql[2];
    {
        const float* qsrc = Q + ((size_t)(b * kS + q0 + w * 16 + lm)) * kE + h * kD + g * 8;
#pragma unroll
        for (int ks = 0; ks < 2; ++ks) {
            float f[8];
            *(float4*)&f[0] = *(const float4*)(qsrc + 32 * ks);
            *(float4*)&f[4] = *(const float4*)(qsrc + 32 * ks + 4);
            bf16x8 hv, lv;
#pragma unroll
            for (int j = 0; j < 8; ++j) { __bf16 a, c; split_bf16(f[j], a, c); hv[j] = a; lv[j] = c; }
            qh[ks] = hv; ql[ks] = lv;
        }
    }

    const f32x4 zero4 = {0.f, 0.f, 0.f, 0.f};
    f32x4 oacc[4];   // O^T frag mt: d = 16*mt + g*4 + jj, q = lm
#pragma unroll
    for (int i = 0; i < 4; ++i) oacc[i] = zero4;
    float mrun = -INFINITY, lsum = 0.f;

    for (int k0 = 0; k0 < kS; k0 += 64) {
        __syncthreads();   // previous tile fully consumed
        // ---- stage K (hi+lo, swizzled rows [key][d]) ----
        {
            const int key = tid >> 2;
            const float* src = x + ((size_t)(b * kS + k0 + key)) * kE + h * kD;
#pragma unroll
            for (int cc = 0; cc < 2; ++cc) {
                const int c = (tid & 3) + 4 * cc;
                float f[8];
                *(float4*)&f[0] = *(const float4*)(src + c * 8);
                *(float4*)&f[4] = *(const float4*)(src + c * 8 + 4);
                bf16x8 hv, lv;
#pragma unroll
                for (int j = 0; j < 8; ++j) { __bf16 a, d2; split_bf16(f[j], a, d2); hv[j] = a; lv[j] = d2; }
                const int dst = key * 64 + ((c ^ (key & 7)) * 8);
                *(bf16x8*)&Ksh[dst] = hv;
                *(bf16x8*)&Ksl[dst] = lv;
            }
            // ---- stage V transposed: Vt[d][key], 4x4 register transpose ----
            const int dt = tid & 15, kt = tid >> 4;
            const float* vsrc = V + ((size_t)(b * kS + k0 + 4 * kt)) * kE + h * kD + 4 * dt;
            const float4 r0 = *(const float4*)vsrc;
            const float4 r1 = *(const float4*)(vsrc + kE);
            const float4 r2 = *(const float4*)(vsrc + 2 * kE);
            const float4 r3 = *(const float4*)(vsrc + 3 * kE);
            const float rr[4][4] = {{r0.x, r0.y, r0.z, r0.w},
                                    {r1.x, r1.y, r1.z, r1.w},
                                    {r2.x, r2.y, r2.z, r2.w},
                                    {r3.x, r3.y, r3.z, r3.w}};
#pragma unroll
            for (int jd = 0; jd < 4; ++jd) {
                const int d = 4 * dt + jd;
                bf16x4 vv = {(__bf16)rr[0][jd], (__bf16)rr[1][jd],
                             (__bf16)rr[2][jd], (__bf16)rr[3][jd]};
                const int adr = d * 64 + (((kt >> 1) ^ (d & 7)) * 8) + (kt & 1) * 4;
                *(bf16x4*)&Vt[adr] = vv;
            }
        }
        __syncthreads();

        // ---- QK^T swapped: S^T[key = 16mt + g*4+jj][q = lm] ----
        f32x4 sacc[4];
#pragma unroll
        for (int i = 0; i < 4; ++i) sacc[i] = zero4;
#pragma unroll
        for (int mt = 0; mt < 4; ++mt) {
            const int key = 16 * mt + lm;
#pragma unroll
            for (int ks = 0; ks < 2; ++ks) {
                const int adr = key * 64 + (((g + 4 * ks) ^ (key & 7)) * 8);
                bf16x8 kh = *(const bf16x8*)&Ksh[adr];
                bf16x8 kl = *(const bf16x8*)&Ksl[adr];
                sacc[mt] = __builtin_amdgcn_mfma_f32_16x16x32_bf16(kh, qh[ks], sacc[mt], 0, 0, 0);
                sacc[mt] = __builtin_amdgcn_mfma_f32_16x16x32_bf16(kh, ql[ks], sacc[mt], 0, 0, 0);
                sacc[mt] = __builtin_amdgcn_mfma_f32_16x16x32_bf16(kl, qh[ks], sacc[mt], 0, 0, 0);
            }
        }

        // ---- online softmax (scores already in log2 space) ----
        float tmax = -INFINITY;
#pragma unroll
        for (int mt = 0; mt < 4; ++mt)
#pragma unroll
            for (int jj = 0; jj < 4; ++jj) tmax = fmaxf(tmax, sacc[mt][jj]);
        tmax = fmaxf(tmax, __shfl_xor(tmax, 16));
        tmax = fmaxf(tmax, __shfl_xor(tmax, 32));
        const float mnew = fmaxf(mrun, tmax);
        const float alpha = exp2f(mrun - mnew);
        float tsum = 0.f;
        __bf16 pb[16];
#pragma unroll
        for (int mt = 0; mt < 4; ++mt)
#pragma unroll
            for (int jj = 0; jj < 4; ++jj) {
                const float p = exp2f(sacc[mt][jj] - mnew);
                tsum += p;
                pb[mt * 4 + jj] = (__bf16)p;
            }
        tsum += __shfl_xor(tsum, 16);
        tsum += __shfl_xor(tsum, 32);
        lsum = lsum * alpha + tsum;
        mrun = mnew;
#pragma unroll
        for (int i = 0; i < 4; ++i) oacc[i] *= alpha;

        // ---- write P[q = lm][key] (bf16, swizzled) ----
#pragma unroll
        for (int mt = 0; mt < 4; ++mt) {
            bf16x4 pv = {pb[mt * 4], pb[mt * 4 + 1], pb[mt * 4 + 2], pb[mt * 4 + 3]};
            const int chunk = 2 * mt + (g >> 1);
            const int adr = lm * 64 + ((chunk ^ (lm & 7)) * 8) + (g & 1) * 4;
            *(bf16x4*)&Pl[w][adr] = pv;
        }

        // ---- PV: O^T[d][q] += Vt · P^T ----
#pragma unroll
        for (int mt = 0; mt < 4; ++mt) {
            const int d = 16 * mt + lm;
#pragma unroll
            for (int ks = 0; ks < 2; ++ks) {
                const int p = g + 4 * ks;
                bf16x8 vv = *(const bf16x8*)&Vt[d * 64 + ((p ^ (d & 7)) * 8)];
                bf16x8 pf = *(const bf16x8*)&Pl[w][lm * 64 + ((p ^ (lm & 7)) * 8)];
                oacc[mt] = __builtin_amdgcn_mfma_f32_16x16x32_bf16(vv, pf, oacc[mt], 0, 0, 0);
            }
        }
    }

    const float inv = 1.0f / lsum;
    float* dst = O + ((size_t)(b * kS + q0 + w * 16 + lm)) * kE + h * kD;
#pragma unroll
    for (int mt = 0; mt < 4; ++mt)
#pragma unroll
        for (int jj = 0; jj < 4; ++jj)
            dst[16 * mt + g * 4 + jj] = oacc[mt][jj] * inv;
}

// ---------------------------------------------------------------------------
extern "C" void kernel_launch(void* const* d_in, const int* in_sizes, int n_in,
                              void* d_out, int out_size, void* d_ws, size_t ws_size,
                              hipStream_t stream) {
    (void)in_sizes; (void)n_in; (void)out_size; (void)ws_size;
    const float* x      = (const float*)d_in[0];
    const float* params = (const float*)d_in[1];
    const float* Wv     = (const float*)d_in[2];
    const float* bv     = (const float*)d_in[3];
    const float* Wo     = (const float*)d_in[4];
    const float* bo     = (const float*)d_in[5];
    float* out = (float*)d_out;

    char* ws = (char*)d_ws;
    float* wqk = (float*)ws;                                  // 256 KB
    float* Q   = (float*)(ws + 262144);                       // 16 MB
    float* V   = Q + (size_t)kB * kS * kE;                    // 16 MB
    float* AO  = V + (size_t)kB * kS * kE;                    // 16 MB

    build_wqk<<<kH, 256, 0, stream>>>(params, wqk);
    q_proj<<<kB * kS, 256, 0, stream>>>(x, wqk, Q);
    gemm_bt_bias<<<dim3(kE / 64, (kB * kS) / 64), 256, 0, stream>>>(
        x, Wv, bv, V, kB * kS, kE, kE);
    flash_attn_mfma<<<dim3(kS / 64, kH, kB), 256, 0, stream>>>(Q, x, V, AO);
    gemm_bt_bias<<<dim3(kE / 64, (kB * kS) / 64), 256, 0, stream>>>(
        AO, Wo, bo, out, kB * kS, kE, kE);
}

// Round 3
// 256.103 us; speedup vs baseline: 8.1075x; 2.0630x over previous
//
#include <hip/hip_runtime.h>
#include <math.h>

// Problem constants
static constexpr int kB = 2;
static constexpr int kS = 2048;
static constexpr int kE = 1024;
static constexpr int kH = 16;
static constexpr int kD = 64;
static constexpr int kTRIL = 2080; // 64*65/2

typedef __attribute__((ext_vector_type(8))) __bf16 bf16x8;
typedef __attribute__((ext_vector_type(4))) __bf16 bf16x4;
typedef __attribute__((ext_vector_type(4))) float f32x4;

// Split f32 into bf16 hi (truncation) + bf16 lo (RNE of residual).
__device__ __forceinline__ void split_bf16(float f, __bf16& hi, __bf16& lo) {
    unsigned bits = __builtin_bit_cast(unsigned, f);
    hi = __builtin_bit_cast(__bf16, (unsigned short)(bits >> 16));
    float hf = __builtin_bit_cast(float, bits & 0xFFFF0000u);
    lo = (__bf16)(f - hf);
}

// Async global->LDS 16B copy. LDS dest must be wave-uniform (HW adds lane*16).
__device__ __forceinline__ void gload_lds16(const void* g, void* l) {
    __builtin_amdgcn_global_load_lds(
        (const __attribute__((address_space(1))) unsigned int*)g,
        (__attribute__((address_space(3))) unsigned int*)l, 16, 0, 0);
}

// ---------------------------------------------------------------------------
// Kernel: generic f32 -> (bf16 hi, bf16 lo) split, 4 elements/thread.
// ---------------------------------------------------------------------------
__global__ __launch_bounds__(256) void split_f32_kernel(
    const float* __restrict__ in, __bf16* __restrict__ hi,
    __bf16* __restrict__ lo, int n4)
{
    const int i = blockIdx.x * 256 + threadIdx.x;
    if (i >= n4) return;
    const float4 v = ((const float4*)in)[i];
    const float f[4] = {v.x, v.y, v.z, v.w};
    bf16x4 h, l;
#pragma unroll
    for (int j = 0; j < 4; ++j) { __bf16 a, b; split_bf16(f[j], a, b); h[j] = a; l[j] = b; }
    ((bf16x4*)hi)[i] = h;
    ((bf16x4*)lo)[i] = l;
}

// ---------------------------------------------------------------------------
// Kernel: Wqk[h] = L_h @ L_h^T from packed lower-triangular params.
// ---------------------------------------------------------------------------
__global__ __launch_bounds__(256) void build_wqk(
    const float* __restrict__ params, float* __restrict__ wqk)
{
    __shared__ float p[kTRIL];
    const int h = blockIdx.x;
    for (int i = threadIdx.x; i < kTRIL; i += 256) p[i] = params[h * kTRIL + i];
    __syncthreads();
    for (int idx = threadIdx.x; idx < kD * kD; idx += 256) {
        const int i = idx >> 6;
        const int j = idx & 63;
        const int m = i < j ? i : j;
        const float* pi = p + (i * (i + 1)) / 2;
        const float* pj = p + (j * (j + 1)) / 2;
        float s = 0.f;
        for (int k = 0; k <= m; ++k) s += pi[k] * pj[k];
        wqk[h * kD * kD + idx] = s;
    }
}

// ---------------------------------------------------------------------------
// Kernel: Q = (xh @ Wqk) * 0.125 * log2(e), written as split bf16 (Qh, Ql).
// ---------------------------------------------------------------------------
__global__ __launch_bounds__(256) void q_proj(
    const float* __restrict__ x, const float* __restrict__ wqk,
    __bf16* __restrict__ Qh, __bf16* __restrict__ Ql)
{
    __shared__ float xs[kE];
    const int bs = blockIdx.x;
    const int tid = threadIdx.x;
    ((float4*)xs)[tid] = ((const float4*)(x + (size_t)bs * kE))[tid];
    __syncthreads();
    const int o = tid * 4;
    const int h = o >> 6;
    const int e = o & 63;
    const float* W = wqk + h * kD * kD;
    float a0 = 0.f, a1 = 0.f, a2 = 0.f, a3 = 0.f;
    const float* xh = xs + h * kD;
#pragma unroll 8
    for (int d = 0; d < kD; ++d) {
        const float xv = xh[d];
        const float4 w = *(const float4*)(W + d * kD + e);
        a0 += xv * w.x; a1 += xv * w.y; a2 += xv * w.z; a3 += xv * w.w;
    }
    const float sc = 0.125f * 1.44269504088896340736f;
    const float f[4] = {a0 * sc, a1 * sc, a2 * sc, a3 * sc};
    bf16x4 hv, lv;
#pragma unroll
    for (int j = 0; j < 4; ++j) { __bf16 a, b; split_bf16(f[j], a, b); hv[j] = a; lv[j] = b; }
    ((bf16x4*)(Qh + (size_t)bs * kE))[tid] = hv;
    ((bf16x4*)(Ql + (size_t)bs * kE))[tid] = lv;
}

// ---------------------------------------------------------------------------
// Kernel: split-bf16 MFMA GEMM.  C[M,N] = A @ Bw^T + bias, where
// A ~ Ah+Al, Bw ~ Bh+Bl (bf16 pairs); C = Ah*Bh + Ah*Bl + Al*Bh (f32 acc).
// 128x128 tile, BK=32, 4 waves (2x2), 2-phase double-buffered LDS.
// LDS rows pack hi(4 chunks)+lo(4 chunks) = 128B -> 8-chunk XOR swizzle.
// ---------------------------------------------------------------------------
__global__ __launch_bounds__(256) void gemm_split_mfma(
    const __bf16* __restrict__ Ah, const __bf16* __restrict__ Al,
    const __bf16* __restrict__ Bh, const __bf16* __restrict__ Bl,
    const float* __restrict__ bias, float* __restrict__ C,
    int M, int N, int K)
{
    __shared__ __bf16 Ab[2][128 * 64];
    __shared__ __bf16 Bb[2][128 * 64];

    const int tid = threadIdx.x;
    const int w = tid >> 6, l = tid & 63;
    const int g = l >> 4, lm = l & 15;
    const int wm = w >> 1, wn = w & 1;
    const int bm = blockIdx.y * 128, bn = blockIdx.x * 128;

    const int srow = 8 * w + (l >> 3);  // row within 32-row issue
    const int cp = l & 7;               // LDS chunk position this lane fills

    f32x4 acc[4][4];
#pragma unroll
    for (int i = 0; i < 4; ++i)
#pragma unroll
        for (int j = 0; j < 4; ++j) acc[i][j] = (f32x4){0.f, 0.f, 0.f, 0.f};

    auto stage = [&](int buf, int k0) {
#pragma unroll
        for (int j = 0; j < 4; ++j) {
            const int r = 32 * j + srow;
            const int c = cp ^ (r & 7);          // data chunk at this position
            const int ko = k0 + (c & 3) * 8;     // element offset within row
            const __bf16* sa = (c < 4 ? Ah : Al) + ((size_t)(bm + r) * K + ko);
            gload_lds16(sa, &Ab[buf][j * 2048 + w * 512]);
            const __bf16* sb = (c < 4 ? Bh : Bl) + ((size_t)(bn + r) * K + ko);
            gload_lds16(sb, &Bb[buf][j * 2048 + w * 512]);
        }
    };

    stage(0, 0);
    __syncthreads();
    int cur = 0;
    const int NT = K / 32;
    for (int t = 0; t < NT; ++t) {
        if (t + 1 < NT) stage(cur ^ 1, 32 * (t + 1));

        bf16x8 ah[4], al[4], bh[4], bl[4];
#pragma unroll
        for (int i = 0; i < 4; ++i) {
            const int rA = wm * 64 + i * 16 + lm;
            ah[i] = *(const bf16x8*)&Ab[cur][rA * 64 + ((g ^ (rA & 7)) * 8)];
            al[i] = *(const bf16x8*)&Ab[cur][rA * 64 + (((4 + g) ^ (rA & 7)) * 8)];
            const int rB = wn * 64 + i * 16 + lm;
            bh[i] = *(const bf16x8*)&Bb[cur][rB * 64 + ((g ^ (rB & 7)) * 8)];
            bl[i] = *(const bf16x8*)&Bb[cur][rB * 64 + (((4 + g) ^ (rB & 7)) * 8)];
        }
        // pass 1: Ah*Bh
#pragma unroll
        for (int mi = 0; mi < 4; ++mi)
#pragma unroll
            for (int ni = 0; ni < 4; ++ni)
                acc[mi][ni] = __builtin_amdgcn_mfma_f32_16x16x32_bf16(ah[mi], bh[ni], acc[mi][ni], 0, 0, 0);
        // pass 2: Ah*Bl
#pragma unroll
        for (int mi = 0; mi < 4; ++mi)
#pragma unroll
            for (int ni = 0; ni < 4; ++ni)
                acc[mi][ni] = __builtin_amdgcn_mfma_f32_16x16x32_bf16(ah[mi], bl[ni], acc[mi][ni], 0, 0, 0);
        // pass 3: Al*Bh
#pragma unroll
        for (int mi = 0; mi < 4; ++mi)
#pragma unroll
            for (int ni = 0; ni < 4; ++ni)
                acc[mi][ni] = __builtin_amdgcn_mfma_f32_16x16x32_bf16(al[mi], bh[ni], acc[mi][ni], 0, 0, 0);

        __syncthreads();
        cur ^= 1;
    }

    float bv4[4];
#pragma unroll
    for (int ni = 0; ni < 4; ++ni) bv4[ni] = bias[bn + wn * 64 + ni * 16 + lm];
#pragma unroll
    for (int mi = 0; mi < 4; ++mi) {
        const int row0 = bm + wm * 64 + mi * 16 + g * 4;
#pragma unroll
        for (int r = 0; r < 4; ++r) {
            float* crow = C + (size_t)(row0 + r) * N;
#pragma unroll
            for (int ni = 0; ni < 4; ++ni)
                crow[bn + wn * 64 + ni * 16 + lm] = acc[mi][ni][r] + bv4[ni];
        }
    }
}

// ---------------------------------------------------------------------------
// Kernel: MFMA flash attention (swapped-operand), split-bf16 QK^T.
// Block = 4 waves; BQ=64 (16 q/wave); BK=64. K staged via global_load_lds
// from pre-split xh/xl (inverse-swizzled source + swizzled read).
// Writes attention output as split bf16 (AOh, AOl) for the out-projection.
// ---------------------------------------------------------------------------
__global__ __launch_bounds__(256) void flash_attn_mfma(
    const __bf16* __restrict__ Qh, const __bf16* __restrict__ Ql,
    const __bf16* __restrict__ xh, const __bf16* __restrict__ xl,
    const float* __restrict__ V,
    __bf16* __restrict__ AOh, __bf16* __restrict__ AOl)
{
    __shared__ __bf16 Ksh[64 * 64];
    __shared__ __bf16 Ksl[64 * 64];
    __shared__ __bf16 Vt[64 * 64];      // V transposed: Vt[d][key]
    __shared__ __bf16 Pl[4][16 * 64];   // per-wave P[q][key]

    const int tid = threadIdx.x;
    const int l = tid & 63;
    const int w = tid >> 6;
    const int g = l >> 4;
    const int lm = l & 15;
    const int q0 = blockIdx.x * 64;
    const int h = blockIdx.y;
    const int b = blockIdx.z;

    // Q fragments (hi/lo), persistent: Q[q = q0+16w+lm][d = g*8 + j + 32*ks]
    bf16x8 qh[2], ql[2];
    {
        const size_t qoff = ((size_t)(b * kS + q0 + w * 16 + lm)) * kE + h * kD + g * 8;
#pragma unroll
        for (int ks = 0; ks < 2; ++ks) {
            qh[ks] = *(const bf16x8*)(Qh + qoff + 32 * ks);
            ql[ks] = *(const bf16x8*)(Ql + qoff + 32 * ks);
        }
    }

    const f32x4 zero4 = {0.f, 0.f, 0.f, 0.f};
    f32x4 oacc[4];   // O^T frag mt: d = 16*mt + g*4 + jj, q = lm
#pragma unroll
    for (int i = 0; i < 4; ++i) oacc[i] = zero4;
    float mrun = -INFINITY, lsum = 0.f;

    const int srow = 8 * w + (l >> 3);
    const int cpos = l & 7;

    for (int k0 = 0; k0 < kS; k0 += 64) {
        __syncthreads();   // previous tile fully consumed
        // ---- stage K hi/lo via global_load_lds (inverse-swizzled source) ----
#pragma unroll
        for (int j = 0; j < 2; ++j) {
            const int r = 32 * j + srow;
            const int c = cpos ^ (r & 7);
            const size_t goff = ((size_t)(b * kS + k0 + r)) * kE + h * kD + c * 8;
            gload_lds16(xh + goff, &Ksh[j * 2048 + w * 512]);
            gload_lds16(xl + goff, &Ksl[j * 2048 + w * 512]);
        }
        // ---- stage V transposed: Vt[d][key], 4x4 register transpose ----
        {
            const int dt = tid & 15, kt = tid >> 4;
            const float* vsrc = V + ((size_t)(b * kS + k0 + 4 * kt)) * kE + h * kD + 4 * dt;
            const float4 r0 = *(const float4*)vsrc;
            const float4 r1 = *(const float4*)(vsrc + kE);
            const float4 r2 = *(const float4*)(vsrc + 2 * kE);
            const float4 r3 = *(const float4*)(vsrc + 3 * kE);
            const float rr[4][4] = {{r0.x, r0.y, r0.z, r0.w},
                                    {r1.x, r1.y, r1.z, r1.w},
                                    {r2.x, r2.y, r2.z, r2.w},
                                    {r3.x, r3.y, r3.z, r3.w}};
#pragma unroll
            for (int jd = 0; jd < 4; ++jd) {
                const int d = 4 * dt + jd;
                bf16x4 vv = {(__bf16)rr[0][jd], (__bf16)rr[1][jd],
                             (__bf16)rr[2][jd], (__bf16)rr[3][jd]};
                const int adr = d * 64 + (((kt >> 1) ^ (d & 7)) * 8) + (kt & 1) * 4;
                *(bf16x4*)&Vt[adr] = vv;
            }
        }
        __syncthreads();

        // ---- QK^T swapped: S^T[key = 16mt + g*4+jj][q = lm] ----
        f32x4 sacc[4];
#pragma unroll
        for (int i = 0; i < 4; ++i) sacc[i] = zero4;
#pragma unroll
        for (int mt = 0; mt < 4; ++mt) {
            const int key = 16 * mt + lm;
#pragma unroll
            for (int ks = 0; ks < 2; ++ks) {
                const int adr = key * 64 + (((g + 4 * ks) ^ (key & 7)) * 8);
                bf16x8 kh = *(const bf16x8*)&Ksh[adr];
                bf16x8 kl = *(const bf16x8*)&Ksl[adr];
                sacc[mt] = __builtin_amdgcn_mfma_f32_16x16x32_bf16(kh, qh[ks], sacc[mt], 0, 0, 0);
                sacc[mt] = __builtin_amdgcn_mfma_f32_16x16x32_bf16(kh, ql[ks], sacc[mt], 0, 0, 0);
                sacc[mt] = __builtin_amdgcn_mfma_f32_16x16x32_bf16(kl, qh[ks], sacc[mt], 0, 0, 0);
            }
        }

        // ---- online softmax (scores already in log2 space) ----
        float tmax = -INFINITY;
#pragma unroll
        for (int mt = 0; mt < 4; ++mt)
#pragma unroll
            for (int jj = 0; jj < 4; ++jj) tmax = fmaxf(tmax, sacc[mt][jj]);
        tmax = fmaxf(tmax, __shfl_xor(tmax, 16));
        tmax = fmaxf(tmax, __shfl_xor(tmax, 32));
        const float mnew = fmaxf(mrun, tmax);
        const float alpha = exp2f(mrun - mnew);
        float tsum = 0.f;
        __bf16 pb[16];
#pragma unroll
        for (int mt = 0; mt < 4; ++mt)
#pragma unroll
            for (int jj = 0; jj < 4; ++jj) {
                const float p = exp2f(sacc[mt][jj] - mnew);
                tsum += p;
                pb[mt * 4 + jj] = (__bf16)p;
            }
        tsum += __shfl_xor(tsum, 16);
        tsum += __shfl_xor(tsum, 32);
        lsum = lsum * alpha + tsum;
        mrun = mnew;
#pragma unroll
        for (int i = 0; i < 4; ++i) oacc[i] *= alpha;

        // ---- write P[q = lm][key] (bf16, swizzled) ----
#pragma unroll
        for (int mt = 0; mt < 4; ++mt) {
            bf16x4 pv = {pb[mt * 4], pb[mt * 4 + 1], pb[mt * 4 + 2], pb[mt * 4 + 3]};
            const int chunk = 2 * mt + (g >> 1);
            const int adr = lm * 64 + ((chunk ^ (lm & 7)) * 8) + (g & 1) * 4;
            *(bf16x4*)&Pl[w][adr] = pv;
        }

        // ---- PV: O^T[d][q] += Vt . P^T ----
#pragma unroll
        for (int mt = 0; mt < 4; ++mt) {
            const int d = 16 * mt + lm;
#pragma unroll
            for (int ks = 0; ks < 2; ++ks) {
                const int p = g + 4 * ks;
                bf16x8 vv = *(const bf16x8*)&Vt[d * 64 + ((p ^ (d & 7)) * 8)];
                bf16x8 pf = *(const bf16x8*)&Pl[w][lm * 64 + ((p ^ (lm & 7)) * 8)];
                oacc[mt] = __builtin_amdgcn_mfma_f32_16x16x32_bf16(vv, pf, oacc[mt], 0, 0, 0);
            }
        }
    }

    const float inv = 1.0f / lsum;
    const size_t obase = ((size_t)(b * kS + q0 + w * 16 + lm)) * kE + h * kD;
#pragma unroll
    for (int mt = 0; mt < 4; ++mt) {
        bf16x4 hv, lv;
#pragma unroll
        for (int jj = 0; jj < 4; ++jj) {
            __bf16 a, c;
            split_bf16(oacc[mt][jj] * inv, a, c);
            hv[jj] = a; lv[jj] = c;
        }
        *(bf16x4*)(AOh + obase + 16 * mt + 4 * g) = hv;
        *(bf16x4*)(AOl + obase + 16 * mt + 4 * g) = lv;
    }
}

// ---------------------------------------------------------------------------
extern "C" void kernel_launch(void* const* d_in, const int* in_sizes, int n_in,
                              void* d_out, int out_size, void* d_ws, size_t ws_size,
                              hipStream_t stream) {
    (void)in_sizes; (void)n_in; (void)out_size; (void)ws_size;
    const float* x      = (const float*)d_in[0];
    const float* params = (const float*)d_in[1];
    const float* Wv     = (const float*)d_in[2];
    const float* bv     = (const float*)d_in[3];
    const float* Wo     = (const float*)d_in[4];
    const float* bo     = (const float*)d_in[5];
    float* out = (float*)d_out;

    const size_t NE = (size_t)kB * kS * kE;   // 4194304
    const size_t NW = (size_t)kE * kE;        // 1048576

    char* ws = (char*)d_ws;
    size_t off = 0;
    float*  wqk = (float*)(ws + off);  off += (size_t)kH * kD * kD * 4;  // 256KB
    __bf16* xh  = (__bf16*)(ws + off); off += NE * 2;                    // 8MB
    __bf16* xl  = (__bf16*)(ws + off); off += NE * 2;
    __bf16* wvh = (__bf16*)(ws + off); off += NW * 2;                    // 2MB
    __bf16* wvl = (__bf16*)(ws + off); off += NW * 2;
    __bf16* woh = (__bf16*)(ws + off); off += NW * 2;
    __bf16* wol = (__bf16*)(ws + off); off += NW * 2;
    __bf16* Qh  = (__bf16*)(ws + off); off += NE * 2;
    __bf16* Ql  = (__bf16*)(ws + off); off += NE * 2;
    float*  V   = (float*)(ws + off);  off += NE * 4;                    // 16MB
    __bf16* AOh = (__bf16*)(ws + off); off += NE * 2;
    __bf16* AOl = (__bf16*)(ws + off); off += NE * 2;

    split_f32_kernel<<<(int)(NE / 4 / 256), 256, 0, stream>>>(x, xh, xl, (int)(NE / 4));
    split_f32_kernel<<<(int)(NW / 4 / 256), 256, 0, stream>>>(Wv, wvh, wvl, (int)(NW / 4));
    split_f32_kernel<<<(int)(NW / 4 / 256), 256, 0, stream>>>(Wo, woh, wol, (int)(NW / 4));
    build_wqk<<<kH, 256, 0, stream>>>(params, wqk);
    q_proj<<<kB * kS, 256, 0, stream>>>(x, wqk, Qh, Ql);
    gemm_split_mfma<<<dim3(kE / 128, (kB * kS) / 128), 256, 0, stream>>>(
        xh, xl, wvh, wvl, bv, V, kB * kS, kE, kE);
    flash_attn_mfma<<<dim3(kS / 64, kH, kB), 256, 0, stream>>>(Qh, Ql, xh, xl, V, AOh, AOl);
    gemm_split_mfma<<<dim3(kE / 128, (kB * kS) / 128), 256, 0, stream>>>(
        AOh, AOl, woh, wol, bo, out, kB * kS, kE, kE);
}

// Round 4
// 199.250 us; speedup vs baseline: 10.4209x; 1.2853x over previous
//
#include <hip/hip_runtime.h>
#include <math.h>

// Problem constants
static constexpr int kB = 2;
static constexpr int kS = 2048;
static constexpr int kE = 1024;
static constexpr int kH = 16;
static constexpr int kD = 64;
static constexpr int kTRIL = 2080; // 64*65/2

typedef __attribute__((ext_vector_type(8))) __bf16 bf16x8;
typedef __attribute__((ext_vector_type(4))) __bf16 bf16x4;
typedef __attribute__((ext_vector_type(4))) float f32x4;

// Split f32 into bf16 hi (truncation) + bf16 lo (RNE of residual).
__device__ __forceinline__ void split_bf16(float f, __bf16& hi, __bf16& lo) {
    unsigned bits = __builtin_bit_cast(unsigned, f);
    hi = __builtin_bit_cast(__bf16, (unsigned short)(bits >> 16));
    float hf = __builtin_bit_cast(float, bits & 0xFFFF0000u);
    lo = (__bf16)(f - hf);
}

// Async global->LDS 16B copy. LDS dest is wave-uniform (HW adds lane*16).
__device__ __forceinline__ void gload_lds16(const void* g, void* l) {
    __builtin_amdgcn_global_load_lds(
        (const __attribute__((address_space(1))) unsigned int*)g,
        (__attribute__((address_space(3))) unsigned int*)l, 16, 0, 0);
}

// ---------------------------------------------------------------------------
// f32 -> (bf16 hi trunc, bf16 lo) split, 4 elems/thread (x only, for QK^T).
// ---------------------------------------------------------------------------
__global__ __launch_bounds__(256) void split_f32_kernel(
    const float* __restrict__ in, __bf16* __restrict__ hi,
    __bf16* __restrict__ lo, int n4)
{
    const int i = blockIdx.x * 256 + threadIdx.x;
    if (i >= n4) return;
    const float4 v = ((const float4*)in)[i];
    const float f[4] = {v.x, v.y, v.z, v.w};
    bf16x4 h, l;
#pragma unroll
    for (int j = 0; j < 4; ++j) { __bf16 a, b; split_bf16(f[j], a, b); h[j] = a; l[j] = b; }
    ((bf16x4*)hi)[i] = h;
    ((bf16x4*)lo)[i] = l;
}

// ---------------------------------------------------------------------------
// f32 -> bf16 (RNE), 4 elems/thread (for Wv, Wo).
// ---------------------------------------------------------------------------
__global__ __launch_bounds__(256) void cast_bf16_kernel(
    const float* __restrict__ in, __bf16* __restrict__ out, int n4)
{
    const int i = blockIdx.x * 256 + threadIdx.x;
    if (i >= n4) return;
    const float4 v = ((const float4*)in)[i];
    bf16x4 o = {(__bf16)v.x, (__bf16)v.y, (__bf16)v.z, (__bf16)v.w};
    ((bf16x4*)out)[i] = o;
}

// ---------------------------------------------------------------------------
// Wqk[h] = L_h @ L_h^T from packed lower-triangular params.
// ---------------------------------------------------------------------------
__global__ __launch_bounds__(256) void build_wqk(
    const float* __restrict__ params, float* __restrict__ wqk)
{
    __shared__ float p[kTRIL];
    const int h = blockIdx.x;
    for (int i = threadIdx.x; i < kTRIL; i += 256) p[i] = params[h * kTRIL + i];
    __syncthreads();
    for (int idx = threadIdx.x; idx < kD * kD; idx += 256) {
        const int i = idx >> 6;
        const int j = idx & 63;
        const int m = i < j ? i : j;
        const float* pi = p + (i * (i + 1)) / 2;
        const float* pj = p + (j * (j + 1)) / 2;
        float s = 0.f;
        for (int k = 0; k <= m; ++k) s += pi[k] * pj[k];
        wqk[h * kD * kD + idx] = s;
    }
}

// ---------------------------------------------------------------------------
// Q = (xh @ Wqk) * 0.125 * log2(e), written as split bf16 (Qh, Ql).
// ---------------------------------------------------------------------------
__global__ __launch_bounds__(256) void q_proj(
    const float* __restrict__ x, const float* __restrict__ wqk,
    __bf16* __restrict__ Qh, __bf16* __restrict__ Ql)
{
    __shared__ float xs[kE];
    const int bs = blockIdx.x;
    const int tid = threadIdx.x;
    ((float4*)xs)[tid] = ((const float4*)(x + (size_t)bs * kE))[tid];
    __syncthreads();
    const int o = tid * 4;
    const int h = o >> 6;
    const int e = o & 63;
    const float* W = wqk + h * kD * kD;
    float a0 = 0.f, a1 = 0.f, a2 = 0.f, a3 = 0.f;
    const float* xh = xs + h * kD;
#pragma unroll 8
    for (int d = 0; d < kD; ++d) {
        const float xv = xh[d];
        const float4 w = *(const float4*)(W + d * kD + e);
        a0 += xv * w.x; a1 += xv * w.y; a2 += xv * w.z; a3 += xv * w.w;
    }
    const float sc = 0.125f * 1.44269504088896340736f;
    const float f[4] = {a0 * sc, a1 * sc, a2 * sc, a3 * sc};
    bf16x4 hv, lv;
#pragma unroll
    for (int j = 0; j < 4; ++j) { __bf16 a, b; split_bf16(f[j], a, b); hv[j] = a; lv[j] = b; }
    ((bf16x4*)(Qh + (size_t)bs * kE))[tid] = hv;
    ((bf16x4*)(Ql + (size_t)bs * kE))[tid] = lv;
}

// ---------------------------------------------------------------------------
// Single-pass bf16 MFMA GEMM: C = A @ Bw^T + bias (f32 accumulate).
// 128x128 tile, BK=64, 4 waves (2x2), 2-phase double-buffered global_load_lds.
// LDS rows = 64 bf16 (128B), 8 x 16B chunks, XOR swizzle chunk^(row&7).
// MODE 0: C f32 [M,N].  MODE 1: C bf16 transposed to Vt[b,h,d,s].
// ---------------------------------------------------------------------------
template <int MODE>
__global__ __launch_bounds__(256) void gemm_bf16(
    const __bf16* __restrict__ A, const __bf16* __restrict__ Bw,
    const float* __restrict__ bias, void* __restrict__ Cout,
    int M, int N, int K)
{
    __shared__ __bf16 Ab[2][128 * 64];
    __shared__ __bf16 Bb[2][128 * 64];

    const int tid = threadIdx.x;
    const int w = tid >> 6, l = tid & 63;
    const int g = l >> 4, lm = l & 15;
    const int wm = w >> 1, wn = w & 1;
    const int bm = blockIdx.y * 128, bn = blockIdx.x * 128;
    const int srow = 8 * w + (l >> 3);
    const int cp = l & 7;

    f32x4 acc[4][4];
#pragma unroll
    for (int i = 0; i < 4; ++i)
#pragma unroll
        for (int j = 0; j < 4; ++j) acc[i][j] = (f32x4){0.f, 0.f, 0.f, 0.f};

    auto stage = [&](int buf, int k0) {
#pragma unroll
        for (int j = 0; j < 4; ++j) {
            const int r = 32 * j + srow;
            const int c = cp ^ (r & 7);
            gload_lds16(A + (size_t)(bm + r) * K + k0 + c * 8, &Ab[buf][j * 2048 + w * 512]);
            gload_lds16(Bw + (size_t)(bn + r) * K + k0 + c * 8, &Bb[buf][j * 2048 + w * 512]);
        }
    };

    stage(0, 0);
    __syncthreads();
    int cur = 0;
    const int NT = K / 64;
    for (int t = 0; t < NT; ++t) {
        if (t + 1 < NT) stage(cur ^ 1, 64 * (t + 1));

        bf16x8 a[4][2], bf[4][2];
#pragma unroll
        for (int i = 0; i < 4; ++i) {
            const int rA = wm * 64 + i * 16 + lm;
            const int rB = wn * 64 + i * 16 + lm;
#pragma unroll
            for (int ks = 0; ks < 2; ++ks) {
                a[i][ks]  = *(const bf16x8*)&Ab[cur][rA * 64 + (((4 * ks + g) ^ (rA & 7)) * 8)];
                bf[i][ks] = *(const bf16x8*)&Bb[cur][rB * 64 + (((4 * ks + g) ^ (rB & 7)) * 8)];
            }
        }
#pragma unroll
        for (int ks = 0; ks < 2; ++ks)
#pragma unroll
            for (int mi = 0; mi < 4; ++mi)
#pragma unroll
                for (int ni = 0; ni < 4; ++ni)
                    acc[mi][ni] = __builtin_amdgcn_mfma_f32_16x16x32_bf16(
                        a[mi][ks], bf[ni][ks], acc[mi][ni], 0, 0, 0);

        __syncthreads();
        cur ^= 1;
    }

    if (MODE == 0) {
        float bv4[4];
#pragma unroll
        for (int ni = 0; ni < 4; ++ni) bv4[ni] = bias[bn + wn * 64 + ni * 16 + lm];
        float* C = (float*)Cout;
#pragma unroll
        for (int mi = 0; mi < 4; ++mi) {
            const int row0 = bm + wm * 64 + mi * 16 + g * 4;
#pragma unroll
            for (int r = 0; r < 4; ++r) {
                float* crow = C + (size_t)(row0 + r) * N;
#pragma unroll
                for (int ni = 0; ni < 4; ++ni)
                    crow[bn + wn * 64 + ni * 16 + lm] = acc[mi][ni][r] + bv4[ni];
            }
        }
    } else {
        __bf16* Vt = (__bf16*)Cout;
#pragma unroll
        for (int ni = 0; ni < 4; ++ni) {
            const int col = bn + wn * 64 + ni * 16 + lm;
            const float bb = bias[col];
            const int hh = col >> 6, dd = col & 63;
#pragma unroll
            for (int mi = 0; mi < 4; ++mi) {
                const int tok = bm + wm * 64 + mi * 16 + g * 4;
                const int b = tok >> 11, s0 = tok & 2047;
                bf16x4 pk;
#pragma unroll
                for (int r = 0; r < 4; ++r) pk[r] = (__bf16)(acc[mi][ni][r] + bb);
                *(bf16x4*)(Vt + ((size_t)(b * kH + hh) * kD + dd) * kS + s0) = pk;
            }
        }
    }
}

// ---------------------------------------------------------------------------
// MFMA flash attention (swapped-operand), split-bf16 QK^T, bf16 V^T input.
// Block = 4 waves; BQ=64 (16 q/wave); BK=64. All tiles staged via
// global_load_lds with inverse-swizzled source + swizzled reads.
// Defer-max online softmax (THR=8 in log2 units). Output: AO bf16 (RNE).
// ---------------------------------------------------------------------------
__global__ __launch_bounds__(256) void flash_attn_mfma(
    const __bf16* __restrict__ Qh, const __bf16* __restrict__ Ql,
    const __bf16* __restrict__ xh, const __bf16* __restrict__ xl,
    const __bf16* __restrict__ VtG, __bf16* __restrict__ AO)
{
    __shared__ __bf16 Ksh[64 * 64];
    __shared__ __bf16 Ksl[64 * 64];
    __shared__ __bf16 Vt[64 * 64];      // Vt[d][key] for this tile
    __shared__ __bf16 Pl[4][16 * 64];   // per-wave P[q][key]

    const int tid = threadIdx.x;
    const int l = tid & 63;
    const int w = tid >> 6;
    const int g = l >> 4;
    const int lm = l & 15;
    const int q0 = blockIdx.x * 64;
    const int h = blockIdx.y;
    const int b = blockIdx.z;

    // Q fragments (hi/lo), persistent.
    bf16x8 qh[2], ql[2];
    {
        const size_t qoff = ((size_t)(b * kS + q0 + w * 16 + lm)) * kE + h * kD + g * 8;
#pragma unroll
        for (int ks = 0; ks < 2; ++ks) {
            qh[ks] = *(const bf16x8*)(Qh + qoff + 32 * ks);
            ql[ks] = *(const bf16x8*)(Ql + qoff + 32 * ks);
        }
    }

    const f32x4 zero4 = {0.f, 0.f, 0.f, 0.f};
    f32x4 oacc[4];
#pragma unroll
    for (int i = 0; i < 4; ++i) oacc[i] = zero4;
    float mrun = -INFINITY, lsum = 0.f;

    const int srow = 8 * w + (l >> 3);
    const int cpos = l & 7;
    const size_t vthead = ((size_t)(b * kH + h) * kD) * kS;

    for (int k0 = 0; k0 < kS; k0 += 64) {
        __syncthreads();   // previous tile fully consumed
        // ---- stage K hi/lo and Vt rows via global_load_lds ----
#pragma unroll
        for (int j = 0; j < 2; ++j) {
            const int r = 32 * j + srow;
            const int c = cpos ^ (r & 7);
            const size_t goff = ((size_t)(b * kS + k0 + r)) * kE + h * kD + c * 8;
            gload_lds16(xh + goff, &Ksh[j * 2048 + w * 512]);
            gload_lds16(xl + goff, &Ksl[j * 2048 + w * 512]);
            const size_t voff = vthead + (size_t)r * kS + k0 + c * 8;
            gload_lds16(VtG + voff, &Vt[j * 2048 + w * 512]);
        }
        __syncthreads();

        // ---- QK^T swapped (3-pass split): S^T[key=16mt+g*4+jj][q=lm] ----
        f32x4 sacc[4];
#pragma unroll
        for (int i = 0; i < 4; ++i) sacc[i] = zero4;
#pragma unroll
        for (int mt = 0; mt < 4; ++mt) {
            const int key = 16 * mt + lm;
#pragma unroll
            for (int ks = 0; ks < 2; ++ks) {
                const int adr = key * 64 + (((4 * ks + g) ^ (key & 7)) * 8);
                bf16x8 kh = *(const bf16x8*)&Ksh[adr];
                bf16x8 kl = *(const bf16x8*)&Ksl[adr];
                sacc[mt] = __builtin_amdgcn_mfma_f32_16x16x32_bf16(kh, qh[ks], sacc[mt], 0, 0, 0);
                sacc[mt] = __builtin_amdgcn_mfma_f32_16x16x32_bf16(kh, ql[ks], sacc[mt], 0, 0, 0);
                sacc[mt] = __builtin_amdgcn_mfma_f32_16x16x32_bf16(kl, qh[ks], sacc[mt], 0, 0, 0);
            }
        }

        // ---- online softmax with defer-max (log2 space) ----
        float tmax = -INFINITY;
#pragma unroll
        for (int mt = 0; mt < 4; ++mt)
#pragma unroll
            for (int jj = 0; jj < 4; ++jj) tmax = fmaxf(tmax, sacc[mt][jj]);
        tmax = fmaxf(tmax, __shfl_xor(tmax, 16));
        tmax = fmaxf(tmax, __shfl_xor(tmax, 32));
        if (__any(tmax > mrun + 8.0f)) {
            const float mnew = fmaxf(mrun, tmax);
            const float alpha = exp2f(mrun - mnew);
            lsum *= alpha;
#pragma unroll
            for (int i = 0; i < 4; ++i) oacc[i] *= alpha;
            mrun = mnew;
        }
        float tsum = 0.f;
        __bf16 pb[16];
#pragma unroll
        for (int mt = 0; mt < 4; ++mt)
#pragma unroll
            for (int jj = 0; jj < 4; ++jj) {
                const float p = exp2f(sacc[mt][jj] - mrun);
                tsum += p;
                pb[mt * 4 + jj] = (__bf16)p;
            }
        tsum += __shfl_xor(tsum, 16);
        tsum += __shfl_xor(tsum, 32);
        lsum += tsum;

        // ---- write P[q=lm][key] (bf16, swizzled) ----
#pragma unroll
        for (int mt = 0; mt < 4; ++mt) {
            bf16x4 pv = {pb[mt * 4], pb[mt * 4 + 1], pb[mt * 4 + 2], pb[mt * 4 + 3]};
            const int chunk = 2 * mt + (g >> 1);
            const int adr = lm * 64 + ((chunk ^ (lm & 7)) * 8) + (g & 1) * 4;
            *(bf16x4*)&Pl[w][adr] = pv;
        }

        // ---- PV: O^T[d][q] += Vt . P^T ----
#pragma unroll
        for (int mt = 0; mt < 4; ++mt) {
            const int d = 16 * mt + lm;
#pragma unroll
            for (int ks = 0; ks < 2; ++ks) {
                const int c = 4 * ks + g;
                bf16x8 vv = *(const bf16x8*)&Vt[d * 64 + ((c ^ (d & 7)) * 8)];
                bf16x8 pf = *(const bf16x8*)&Pl[w][lm * 64 + ((c ^ (lm & 7)) * 8)];
                oacc[mt] = __builtin_amdgcn_mfma_f32_16x16x32_bf16(vv, pf, oacc[mt], 0, 0, 0);
            }
        }
    }

    const float inv = 1.0f / lsum;
    const size_t obase = ((size_t)(b * kS + q0 + w * 16 + lm)) * kE + h * kD;
#pragma unroll
    for (int mt = 0; mt < 4; ++mt) {
        bf16x4 pk;
#pragma unroll
        for (int jj = 0; jj < 4; ++jj) pk[jj] = (__bf16)(oacc[mt][jj] * inv);
        *(bf16x4*)(AO + obase + 16 * mt + 4 * g) = pk;
    }
}

// ---------------------------------------------------------------------------
extern "C" void kernel_launch(void* const* d_in, const int* in_sizes, int n_in,
                              void* d_out, int out_size, void* d_ws, size_t ws_size,
                              hipStream_t stream) {
    (void)in_sizes; (void)n_in; (void)out_size; (void)ws_size;
    const float* x      = (const float*)d_in[0];
    const float* params = (const float*)d_in[1];
    const float* Wv     = (const float*)d_in[2];
    const float* bv     = (const float*)d_in[3];
    const float* Wo     = (const float*)d_in[4];
    const float* bo     = (const float*)d_in[5];
    float* out = (float*)d_out;

    const size_t NE = (size_t)kB * kS * kE;   // 4194304
    const size_t NW = (size_t)kE * kE;        // 1048576

    char* ws = (char*)d_ws;
    size_t off = 0;
    float*  wqk = (float*)(ws + off);  off += (size_t)kH * kD * kD * 4;  // 256KB
    __bf16* xh  = (__bf16*)(ws + off); off += NE * 2;
    __bf16* xl  = (__bf16*)(ws + off); off += NE * 2;
    __bf16* wvb = (__bf16*)(ws + off); off += NW * 2;
    __bf16* wob = (__bf16*)(ws + off); off += NW * 2;
    __bf16* Qh  = (__bf16*)(ws + off); off += NE * 2;
    __bf16* Ql  = (__bf16*)(ws + off); off += NE * 2;
    __bf16* VtG = (__bf16*)(ws + off); off += NE * 2;
    __bf16* AO  = (__bf16*)(ws + off); off += NE * 2;

    split_f32_kernel<<<(int)(NE / 4 / 256), 256, 0, stream>>>(x, xh, xl, (int)(NE / 4));
    cast_bf16_kernel<<<(int)(NW / 4 / 256), 256, 0, stream>>>(Wv, wvb, (int)(NW / 4));
    cast_bf16_kernel<<<(int)(NW / 4 / 256), 256, 0, stream>>>(Wo, wob, (int)(NW / 4));
    build_wqk<<<kH, 256, 0, stream>>>(params, wqk);
    q_proj<<<kB * kS, 256, 0, stream>>>(x, wqk, Qh, Ql);
    gemm_bf16<1><<<dim3(kE / 128, (kB * kS) / 128), 256, 0, stream>>>(
        xh, wvb, bv, (void*)VtG, kB * kS, kE, kE);
    flash_attn_mfma<<<dim3(kS / 64, kH, kB), 256, 0, stream>>>(Qh, Ql, xh, xl, VtG, AO);
    gemm_bf16<0><<<dim3(kE / 128, (kB * kS) / 128), 256, 0, stream>>>(
        AO, wob, bo, (void*)out, kB * kS, kE, kE);
}